// Round 5
// baseline (2541.223 us; speedup 1.0000x reference)
//
#include <hip/hip_runtime.h>
#include <hip/hip_bf16.h>

// RNN scan on MI355X — round 13.
// Ledger: r8/r12 structure is the local optimum (r9 cross-CU sync: 16x loss;
// r10 13/3 split: lost co-wave, +55%; r11 1 wave/SIMD: 2x loss; r12 k1
// retile: neutral). Register file at 2 w/SIMD is FULL (128 arch-VGPR +
// ~192 unified-AGPR wfA) — no reg headroom exists.
// r13 single-variable change in k2's step loop:
//   * k-slice ORDER: LDS-A slices (k in [384,512)) FIRST, then the 12
//     register-A slices. Moves the 20-read LDS burst from right-before-the-
//     tail (where its latency serializes with tanh+barrier every step) to
//     step start (overlaps the first-read latency already paid there).
//   * t=0 k-loop skipped (h_0 = 0; numerically identical).
// k1 kept r12 (x read once; neutral but not worse).

#define T_STEPS 1024
#define HID     512

typedef __attribute__((ext_vector_type(8))) short  short8;   // 8 bf16 (MFMA A/B frag)
typedef __attribute__((ext_vector_type(4))) short  short4_t; // 4 bf16 (8 B)
typedef __attribute__((ext_vector_type(4))) float  f32x4;    // MFMA C/D frag
typedef __attribute__((ext_vector_type(4))) float  float4_t;

typedef unsigned short ushort_t;
typedef unsigned int   uint_t;

__device__ __forceinline__ ushort_t f2bf(float f) {
    union { float f; uint_t u; } c; c.f = f;
    uint_t u = c.u;
    return (ushort_t)((u + 0x7fffu + ((u >> 16) & 1u)) >> 16);   // RNE
}
__device__ __forceinline__ float bf2f(ushort_t h) {
    union { uint_t u; float f; } c; c.u = ((uint_t)h) << 16;
    return c.f;
}
// tanh(x) = 1 - 2/(e^{2x}+1); exp2-based, saturates correctly at +/-1.
__device__ __forceinline__ float tanh_fast(float x) {
    float t = __builtin_amdgcn_exp2f(x * 2.88539008f);   // e^{2x}
    return 1.0f - 2.0f * __builtin_amdgcn_rcpf(t + 1.0f);
}

// ---------------------------------------------------------------------------
// k1: xw[t][b][n] = bf16(x[b,t,:] @ W_x + b_x + b_h). Transposed MFMA:
// A = W_x^T (m = n), B = x^T (n-operand = b).
// Grid (512), 512 threads: WG tile = 2 t x 64 b x 512 n (x read ONCE).
// Wave w: t_loc = w&1, nsub = (w>>1)*128 -> 8 mt x 4 bt acc (128 regs).
// LDS: Wl[512][40] (40 KB) + Xl[2][64][40] (10 KB).
// ---------------------------------------------------------------------------
__global__ __launch_bounds__(512) void k1_xproj(
    const float* __restrict__ x, const float* __restrict__ Wx,
    const float* __restrict__ bx, const float* __restrict__ bh,
    ushort_t* __restrict__ xw)
{
    __shared__ __align__(16) ushort_t Wl[512 * 40];      // [n][k] (k-contig)
    __shared__ __align__(16) ushort_t Xl[2][64 * 40];    // [tt][b][k]

    const int t0    = blockIdx.x * 2;
    const int tid   = threadIdx.x;
    const int wave  = tid >> 6;
    const int lane  = tid & 63;
    const int lm    = lane & 15;
    const int quad  = lane >> 4;
    const int t_loc = wave & 1;
    const int nsub  = (wave >> 1) * 128;

    f32x4 acc[8][4];
    #pragma unroll
    for (int mt = 0; mt < 8; ++mt)
        #pragma unroll
        for (int bt = 0; bt < 4; ++bt) acc[mt][bt] = (f32x4){0.f, 0.f, 0.f, 0.f};

    const int xb = tid >> 3, xc = (tid & 7) * 4;     // X staging: b-row, 4 k's

    for (int kb = 0; kb < 16; ++kb) {
        // ---- stage W_x: 1024 (4n x 4k) tiles, 2 per thread ----
        // loads: float4 along n (coalesced); writes: short4 along k (2-way).
        #pragma unroll
        for (int i = 0; i < 2; ++i) {
            const int c   = i * 512 + tid;
            const int n4  = (c & 127) * 4;       // 4 consecutive n
            const int kg4 = (c >> 7) * 4;        // 4 consecutive k (local)
            float4_t v[4];
            #pragma unroll
            for (int dk = 0; dk < 4; ++dk)
                v[dk] = *(const float4_t*)(Wx + (size_t)(kb * 32 + kg4 + dk) * HID + n4);
            #pragma unroll
            for (int dn = 0; dn < 4; ++dn) {
                short4_t pk;
                #pragma unroll
                for (int dk = 0; dk < 4; ++dk) pk[dk] = (short)f2bf(v[dk][dn]);
                *(short4_t*)&Wl[(n4 + dn) * 40 + kg4] = pk;
            }
        }
        // ---- stage x rows (one float4 per thread per tt) ----
        #pragma unroll
        for (int tt = 0; tt < 2; ++tt) {
            const float* ap = x + ((size_t)xb * T_STEPS + t0 + tt) * HID + kb * 32 + xc;
            float4_t v = *(const float4_t*)ap;
            short4_t pk;
            #pragma unroll
            for (int j = 0; j < 4; ++j) pk[j] = (short)f2bf(v[j]);
            *(short4_t*)&Xl[tt][xb * 40 + xc] = pk;
        }
        __syncthreads();
        short8 afr[8];
        #pragma unroll
        for (int mt = 0; mt < 8; ++mt)
            afr[mt] = *(const short8*)&Wl[(nsub + mt * 16 + lm) * 40 + quad * 8];
        #pragma unroll
        for (int bt = 0; bt < 4; ++bt) {
            short8 bfr = *(const short8*)&Xl[t_loc][(bt * 16 + lm) * 40 + quad * 8];
            #pragma unroll
            for (int mt = 0; mt < 8; ++mt)
                acc[mt][bt] = __builtin_amdgcn_mfma_f32_16x16x32_bf16(afr[mt], bfr, acc[mt][bt], 0, 0, 0);
        }
        __syncthreads();
    }

    // D layout: col = b = lm (+bt*16), row = n_local = quad*4+r (+nsub+mt*16)
    #pragma unroll
    for (int mt = 0; mt < 8; ++mt) {
        float biasv[4];
        #pragma unroll
        for (int r = 0; r < 4; ++r) {
            int n = nsub + mt * 16 + quad * 4 + r;
            biasv[r] = bx[n] + bh[n];
        }
        #pragma unroll
        for (int bt = 0; bt < 4; ++bt) {
            short4_t pk;
            #pragma unroll
            for (int r = 0; r < 4; ++r) pk[r] = (short)f2bf(acc[mt][bt][r] + biasv[r]);
            *(short4_t*)&xw[((size_t)(t0 + t_loc) * 64 + bt * 16 + lm) * HID
                            + nsub + mt * 16 + quad * 4] = pk;
        }
    }
}

// ---------------------------------------------------------------------------
// k2: grid=4 x 512 threads (8 waves, 2/SIMD). Wave owns 64 cols.
// LDS (ushort):
//   hT[2][8192] : h B-frags, frag-linear, double-buffered (2 x 16 KB)
//   Wl[65536]   : W_h A-frags for k in [384,512) (128 KB)
// hT element (b,k): (kt*64 + ((k>>3)&3)*16 + b)*8 + (k&7), kt = k>>5.
// Wl frag c = (ktp*32 + mtg)*64 + l: m = n = mtg*16+(l&15),
//   k = (12+ktp)*32 + (l>>4)*8 + j.
// r13: LDS-A slices run FIRST each step (burst overlaps start-of-step
// latency); loop ends on register-A slices -> no pre-tail read stall.
// ---------------------------------------------------------------------------
__global__ __launch_bounds__(512, 2) void k2_scan(
    const ushort_t* __restrict__ xw, const float* __restrict__ Wh,
    const float* __restrict__ Wfc, const float* __restrict__ bfc,
    float* __restrict__ out)
{
    __shared__ __align__(16) ushort_t hT[2][8192];
    __shared__ __align__(16) ushort_t Wl[65536];

    const int tid  = threadIdx.x;
    const int wave = tid >> 6;
    const int lane = tid & 63;
    const int lm   = lane & 15;
    const int quad = lane >> 4;
    const int rowbase = blockIdx.x * 16;   // batch rows
    const int colb    = wave * 64;         // wave's first output column

    // h_0 = 0 (buffer 0 only; buffer 1 fully written at t=0)
    for (int i = tid; i < 8192; i += 512) hT[0][i] = 0;

    // Wl init: 4*32*64 = 8192 frags
    for (int i = 0; i < 16; ++i) {
        int c   = i * 512 + tid;
        int l   = c & 63;
        int mtg = (c >> 6) & 31;
        int ktp = c >> 11;
        int n   = mtg * 16 + (l & 15);
        int kb  = (12 + ktp) * 32 + (l >> 4) * 8;
        short8 w;
        #pragma unroll
        for (int j = 0; j < 8; ++j) w[j] = (short)f2bf(Wh[(size_t)(kb + j) * HID + n]);
        *(short8*)&Wl[(size_t)c * 8] = w;
    }

    // wfA[mt][kt]: A[m = colb+mt*16+lm][k = kt*32+quad*8+j], k in [0,384).
    // ALL register indices compile-time; 192 frag-regs (unified-file resident).
    short8 wfA[4][12];
    #pragma unroll
    for (int mt = 0; mt < 4; ++mt) {
        const int n = colb + mt * 16 + lm;
        #pragma unroll
        for (int kt = 0; kt < 12; ++kt) {
            short8 w;
            #pragma unroll
            for (int j = 0; j < 8; ++j)
                w[j] = (short)f2bf(Wh[(size_t)(kt * 32 + quad * 8 + j) * HID + n]);
            wfA[mt][kt] = w;
        }
    }
    __syncthreads();

    // strength-reduced xw pointer (per-lane base; bump by 64*HID per step)
    const ushort_t* xp = xw + ((size_t)rowbase + lm) * HID + colb + quad * 4;

    for (int t = 0; t < T_STEPS; ++t, xp += (size_t)64 * HID) {
        // xw loads: one b64 per mt (consumed only pre-tanh -> latency hidden)
        short4_t xv[4];
        #pragma unroll
        for (int mt = 0; mt < 4; ++mt)
            xv[mt] = *(const short4_t*)(xp + mt * 16);

        f32x4 acc[4];
        #pragma unroll
        for (int mt = 0; mt < 4; ++mt) acc[mt] = (f32x4){0.f, 0.f, 0.f, 0.f};

        if (t > 0) {   // h_0 = 0: skip dead k-loop at t=0 (uniform branch)
            const ushort_t* cur = hT[t & 1];
            // k in [384,512) FIRST: A from LDS — the 20-read burst issues at
            // step start, overlapping the first-read latency.
            #pragma unroll
            for (int ktp = 0; ktp < 4; ++ktp) {
                short8 b = *(const short8*)&cur[((12 + ktp) * 64 + lane) * 8];
                #pragma unroll
                for (int mt = 0; mt < 4; ++mt) {
                    short8 a = *(const short8*)&Wl[(size_t)((ktp * 32 + wave * 4 + mt) * 64 + lane) * 8];
                    acc[mt] = __builtin_amdgcn_mfma_f32_16x16x32_bf16(a, b, acc[mt], 0, 0, 0);
                }
            }
            // k in [0,384): A from registers — loop ends with reg-operand
            // MFMAs, no fresh LDS dependency before the tail.
            #pragma unroll
            for (int kt = 0; kt < 12; ++kt) {
                short8 b = *(const short8*)&cur[(kt * 64 + lane) * 8];
                #pragma unroll
                for (int mt = 0; mt < 4; ++mt)
                    acc[mt] = __builtin_amdgcn_mfma_f32_16x16x32_bf16(wfA[mt][kt], b, acc[mt], 0, 0, 0);
            }
        }

        // h_{t+1} = tanh(acc + xw) -> other hT buffer (packed b64 stores)
        ushort_t* nxt = hT[(t + 1) & 1];
        #pragma unroll
        for (int mt = 0; mt < 4; ++mt) {
            float v0 = tanh_fast(acc[mt][0] + bf2f((ushort_t)xv[mt][0]));
            float v1 = tanh_fast(acc[mt][1] + bf2f((ushort_t)xv[mt][1]));
            float v2 = tanh_fast(acc[mt][2] + bf2f((ushort_t)xv[mt][2]));
            float v3 = tanh_fast(acc[mt][3] + bf2f((ushort_t)xv[mt][3]));
            union { short4_t v; __hip_bfloat162 h[2]; } cv;
            cv.h[0] = __float22bfloat162_rn(float2{v0, v1});
            cv.h[1] = __float22bfloat162_rn(float2{v2, v3});
            const int n = colb + mt * 16 + quad * 4;
            *(short4_t*)&nxt[((n >> 5) * 64 + ((n >> 3) & 3) * 16 + lm) * 8 + (n & 7)] = cv.v;
        }

        __syncthreads();   // ONE barrier: h_{t+1} complete before next step reads
    }

    // fused FC epilogue: out[rowbase+b] = h_T[b,:] . W_fc + b_fc
    const ushort_t* fin = hT[T_STEPS & 1];
    #pragma unroll
    for (int bb = 0; bb < 2; ++bb) {
        const int b = wave * 2 + bb;
        short8 hv = *(const short8*)&fin[(((lane >> 2) * 64 + (lane & 3) * 16 + b) * 8)];
        float s = 0.f;
        #pragma unroll
        for (int j = 0; j < 8; ++j) s += bf2f((ushort_t)hv[j]) * Wfc[lane * 8 + j];
        #pragma unroll
        for (int off = 32; off; off >>= 1) s += __shfl_down(s, off, 64);
        if (lane == 0) out[rowbase + b] = s + bfc[0];
    }
}

// ---------------------------------------------------------------------------
extern "C" void kernel_launch(void* const* d_in, const int* in_sizes, int n_in,
                              void* d_out, int out_size, void* d_ws, size_t ws_size,
                              hipStream_t stream)
{
    const float* x   = (const float*)d_in[0];
    const float* Wx  = (const float*)d_in[1];
    const float* bx  = (const float*)d_in[2];
    const float* Wh  = (const float*)d_in[3];
    const float* bh  = (const float*)d_in[4];
    const float* Wfc = (const float*)d_in[5];
    const float* bfc = (const float*)d_in[6];
    float* out = (float*)d_out;

    // ws: xw bf16 [1024 t][64 b][512 n] = 64 MiB
    ushort_t* xw = (ushort_t*)d_ws;

    k1_xproj<<<dim3(512), 512, 0, stream>>>(x, Wx, bx, bh, xw);
    k2_scan <<<dim3(4),   512, 0, stream>>>(xw, Wh, Wfc, bfc, out);
}

// Round 6
// 2247.070 us; speedup vs baseline: 1.1309x; 1.1309x over previous
//
#include <hip/hip_runtime.h>
#include <hip/hip_bf16.h>

// RNN scan on MI355X — round 14.
// Ledger: r9 cross-CU sync 16x loss; r10 13/3 split spilled co-wave; r11
// 1 wave/SIMD 2x loss; r13 k-reorder + t>0 branch -> scratch spills (+1.5MB
// WRITE) and -15%. r12 structure is the proven optimum — k2 below is
// r12-exact EXCEPT one surgical change:
//   xw folded into the MFMA C-operand: acc[mt] starts as f32(xw) (16 lshl
//   replace 16 zero-movs) and the tail loses 16 bf2f + 16 adds. xv rotated
//   one step ahead (prologue loads t=0; step consumes, then loads t+1 into
//   the same 8 regs) — identical k-loop register pressure, no new branches.
// Numerics: fp32 add reorder only (~1e-7) — bf16 quantization dominates.

#define T_STEPS 1024
#define HID     512

typedef __attribute__((ext_vector_type(8))) short  short8;   // 8 bf16 (MFMA A/B frag)
typedef __attribute__((ext_vector_type(4))) short  short4_t; // 4 bf16 (8 B)
typedef __attribute__((ext_vector_type(4))) float  f32x4;    // MFMA C/D frag
typedef __attribute__((ext_vector_type(4))) float  float4_t;

typedef unsigned short ushort_t;
typedef unsigned int   uint_t;

__device__ __forceinline__ ushort_t f2bf(float f) {
    union { float f; uint_t u; } c; c.f = f;
    uint_t u = c.u;
    return (ushort_t)((u + 0x7fffu + ((u >> 16) & 1u)) >> 16);   // RNE
}
__device__ __forceinline__ float bf2f(ushort_t h) {
    union { uint_t u; float f; } c; c.u = ((uint_t)h) << 16;
    return c.f;
}
// tanh(x) = 1 - 2/(e^{2x}+1); exp2-based, saturates correctly at +/-1.
__device__ __forceinline__ float tanh_fast(float x) {
    float t = __builtin_amdgcn_exp2f(x * 2.88539008f);   // e^{2x}
    return 1.0f - 2.0f * __builtin_amdgcn_rcpf(t + 1.0f);
}

// ---------------------------------------------------------------------------
// k1: xw[t][b][n] = bf16(x[b,t,:] @ W_x + b_x + b_h). Transposed MFMA:
// A = W_x^T (m = n), B = x^T (n-operand = b).
// Grid (512), 512 threads: WG tile = 2 t x 64 b x 512 n (x read ONCE).
// Wave w: t_loc = w&1, nsub = (w>>1)*128 -> 8 mt x 4 bt acc (128 regs).
// LDS: Wl[512][40] (40 KB) + Xl[2][64][40] (10 KB).  (r12-exact)
// ---------------------------------------------------------------------------
__global__ __launch_bounds__(512) void k1_xproj(
    const float* __restrict__ x, const float* __restrict__ Wx,
    const float* __restrict__ bx, const float* __restrict__ bh,
    ushort_t* __restrict__ xw)
{
    __shared__ __align__(16) ushort_t Wl[512 * 40];      // [n][k] (k-contig)
    __shared__ __align__(16) ushort_t Xl[2][64 * 40];    // [tt][b][k]

    const int t0    = blockIdx.x * 2;
    const int tid   = threadIdx.x;
    const int wave  = tid >> 6;
    const int lane  = tid & 63;
    const int lm    = lane & 15;
    const int quad  = lane >> 4;
    const int t_loc = wave & 1;
    const int nsub  = (wave >> 1) * 128;

    f32x4 acc[8][4];
    #pragma unroll
    for (int mt = 0; mt < 8; ++mt)
        #pragma unroll
        for (int bt = 0; bt < 4; ++bt) acc[mt][bt] = (f32x4){0.f, 0.f, 0.f, 0.f};

    const int xb = tid >> 3, xc = (tid & 7) * 4;     // X staging: b-row, 4 k's

    for (int kb = 0; kb < 16; ++kb) {
        // ---- stage W_x: 1024 (4n x 4k) tiles, 2 per thread ----
        #pragma unroll
        for (int i = 0; i < 2; ++i) {
            const int c   = i * 512 + tid;
            const int n4  = (c & 127) * 4;       // 4 consecutive n
            const int kg4 = (c >> 7) * 4;        // 4 consecutive k (local)
            float4_t v[4];
            #pragma unroll
            for (int dk = 0; dk < 4; ++dk)
                v[dk] = *(const float4_t*)(Wx + (size_t)(kb * 32 + kg4 + dk) * HID + n4);
            #pragma unroll
            for (int dn = 0; dn < 4; ++dn) {
                short4_t pk;
                #pragma unroll
                for (int dk = 0; dk < 4; ++dk) pk[dk] = (short)f2bf(v[dk][dn]);
                *(short4_t*)&Wl[(n4 + dn) * 40 + kg4] = pk;
            }
        }
        // ---- stage x rows (one float4 per thread per tt) ----
        #pragma unroll
        for (int tt = 0; tt < 2; ++tt) {
            const float* ap = x + ((size_t)xb * T_STEPS + t0 + tt) * HID + kb * 32 + xc;
            float4_t v = *(const float4_t*)ap;
            short4_t pk;
            #pragma unroll
            for (int j = 0; j < 4; ++j) pk[j] = (short)f2bf(v[j]);
            *(short4_t*)&Xl[tt][xb * 40 + xc] = pk;
        }
        __syncthreads();
        short8 afr[8];
        #pragma unroll
        for (int mt = 0; mt < 8; ++mt)
            afr[mt] = *(const short8*)&Wl[(nsub + mt * 16 + lm) * 40 + quad * 8];
        #pragma unroll
        for (int bt = 0; bt < 4; ++bt) {
            short8 bfr = *(const short8*)&Xl[t_loc][(bt * 16 + lm) * 40 + quad * 8];
            #pragma unroll
            for (int mt = 0; mt < 8; ++mt)
                acc[mt][bt] = __builtin_amdgcn_mfma_f32_16x16x32_bf16(afr[mt], bfr, acc[mt][bt], 0, 0, 0);
        }
        __syncthreads();
    }

    // D layout: col = b = lm (+bt*16), row = n_local = quad*4+r (+nsub+mt*16)
    #pragma unroll
    for (int mt = 0; mt < 8; ++mt) {
        float biasv[4];
        #pragma unroll
        for (int r = 0; r < 4; ++r) {
            int n = nsub + mt * 16 + quad * 4 + r;
            biasv[r] = bx[n] + bh[n];
        }
        #pragma unroll
        for (int bt = 0; bt < 4; ++bt) {
            short4_t pk;
            #pragma unroll
            for (int r = 0; r < 4; ++r) pk[r] = (short)f2bf(acc[mt][bt][r] + biasv[r]);
            *(short4_t*)&xw[((size_t)(t0 + t_loc) * 64 + bt * 16 + lm) * HID
                            + nsub + mt * 16 + quad * 4] = pk;
        }
    }
}

// ---------------------------------------------------------------------------
// k2: grid=4 x 512 threads (8 waves, 2/SIMD). Wave owns 64 cols.
// LDS (ushort):
//   hT[2][8192] : h B-frags, frag-linear, double-buffered (2 x 16 KB)
//   Wl[65536]   : W_h A-frags for k in [384,512) (128 KB)
// hT element (b,k): (kt*64 + ((k>>3)&3)*16 + b)*8 + (k&7), kt = k>>5.
// Wl frag c = (ktp*32 + mtg)*64 + l: m = n = mtg*16+(l&15),
//   k = (12+ktp)*32 + (l>>4)*8 + j.
// r14: acc initialized from xw (C-operand folding); xv rotated one step
// ahead. k-loop order and all layouts r12-exact.
// ---------------------------------------------------------------------------
__global__ __launch_bounds__(512, 2) void k2_scan(
    const ushort_t* __restrict__ xw, const float* __restrict__ Wh,
    const float* __restrict__ Wfc, const float* __restrict__ bfc,
    float* __restrict__ out)
{
    __shared__ __align__(16) ushort_t hT[2][8192];
    __shared__ __align__(16) ushort_t Wl[65536];

    const int tid  = threadIdx.x;
    const int wave = tid >> 6;
    const int lane = tid & 63;
    const int lm   = lane & 15;
    const int quad = lane >> 4;
    const int rowbase = blockIdx.x * 16;   // batch rows
    const int colb    = wave * 64;         // wave's first output column

    // h_0 = 0 (buffer 0 only; buffer 1 fully written at t=0)
    for (int i = tid; i < 8192; i += 512) hT[0][i] = 0;

    // Wl init: 4*32*64 = 8192 frags
    for (int i = 0; i < 16; ++i) {
        int c   = i * 512 + tid;
        int l   = c & 63;
        int mtg = (c >> 6) & 31;
        int ktp = c >> 11;
        int n   = mtg * 16 + (l & 15);
        int kb  = (12 + ktp) * 32 + (l >> 4) * 8;
        short8 w;
        #pragma unroll
        for (int j = 0; j < 8; ++j) w[j] = (short)f2bf(Wh[(size_t)(kb + j) * HID + n]);
        *(short8*)&Wl[(size_t)c * 8] = w;
    }

    // wfA[mt][kt]: A[m = colb+mt*16+lm][k = kt*32+quad*8+j], k in [0,384).
    short8 wfA[4][12];
    #pragma unroll
    for (int mt = 0; mt < 4; ++mt) {
        const int n = colb + mt * 16 + lm;
        #pragma unroll
        for (int kt = 0; kt < 12; ++kt) {
            short8 w;
            #pragma unroll
            for (int j = 0; j < 8; ++j)
                w[j] = (short)f2bf(Wh[(size_t)(kt * 32 + quad * 8 + j) * HID + n]);
            wfA[mt][kt] = w;
        }
    }
    __syncthreads();

    // per-lane xw pointer; prologue loads t=0's xv (rotated pipeline).
    const ushort_t* xp = xw + ((size_t)rowbase + lm) * HID + colb + quad * 4;
    short4_t xv[4];
    #pragma unroll
    for (int mt = 0; mt < 4; ++mt)
        xv[mt] = *(const short4_t*)(xp + mt * 16);

    for (int t = 0; t < T_STEPS; ++t) {
        // acc starts as f32(xw[t]) — xw folded into the MFMA C-operand.
        f32x4 acc[4];
        #pragma unroll
        for (int mt = 0; mt < 4; ++mt) {
            acc[mt][0] = bf2f((ushort_t)xv[mt][0]);
            acc[mt][1] = bf2f((ushort_t)xv[mt][1]);
            acc[mt][2] = bf2f((ushort_t)xv[mt][2]);
            acc[mt][3] = bf2f((ushort_t)xv[mt][3]);
        }

        // load xw[t+1] into the same regs (whole k-loop to cover latency;
        // last step re-reads t's own row — safe, unused).
        xp += (size_t)((t == T_STEPS - 1) ? 0 : 64 * HID);
        #pragma unroll
        for (int mt = 0; mt < 4; ++mt)
            xv[mt] = *(const short4_t*)(xp + mt * 16);

        const ushort_t* cur = hT[t & 1];
        // k in [0,384): A from registers, B (h) from LDS
        #pragma unroll
        for (int kt = 0; kt < 12; ++kt) {
            short8 b = *(const short8*)&cur[(kt * 64 + lane) * 8];
            #pragma unroll
            for (int mt = 0; mt < 4; ++mt)
                acc[mt] = __builtin_amdgcn_mfma_f32_16x16x32_bf16(wfA[mt][kt], b, acc[mt], 0, 0, 0);
        }
        // k in [384,512): A from LDS
        #pragma unroll
        for (int ktp = 0; ktp < 4; ++ktp) {
            short8 b = *(const short8*)&cur[((12 + ktp) * 64 + lane) * 8];
            #pragma unroll
            for (int mt = 0; mt < 4; ++mt) {
                short8 a = *(const short8*)&Wl[(size_t)((ktp * 32 + wave * 4 + mt) * 64 + lane) * 8];
                acc[mt] = __builtin_amdgcn_mfma_f32_16x16x32_bf16(a, b, acc[mt], 0, 0, 0);
            }
        }

        // h_{t+1} = tanh(acc) -> other hT buffer (packed b64 stores)
        ushort_t* nxt = hT[(t + 1) & 1];
        #pragma unroll
        for (int mt = 0; mt < 4; ++mt) {
            float v0 = tanh_fast(acc[mt][0]);
            float v1 = tanh_fast(acc[mt][1]);
            float v2 = tanh_fast(acc[mt][2]);
            float v3 = tanh_fast(acc[mt][3]);
            union { short4_t v; __hip_bfloat162 h[2]; } cv;
            cv.h[0] = __float22bfloat162_rn(float2{v0, v1});
            cv.h[1] = __float22bfloat162_rn(float2{v2, v3});
            const int n = colb + mt * 16 + quad * 4;
            *(short4_t*)&nxt[((n >> 5) * 64 + ((n >> 3) & 3) * 16 + lm) * 8 + (n & 7)] = cv.v;
        }

        __syncthreads();   // ONE barrier: h_{t+1} complete before next step reads
    }

    // fused FC epilogue: out[rowbase+b] = h_T[b,:] . W_fc + b_fc
    const ushort_t* fin = hT[T_STEPS & 1];
    #pragma unroll
    for (int bb = 0; bb < 2; ++bb) {
        const int b = wave * 2 + bb;
        short8 hv = *(const short8*)&fin[(((lane >> 2) * 64 + (lane & 3) * 16 + b) * 8)];
        float s = 0.f;
        #pragma unroll
        for (int j = 0; j < 8; ++j) s += bf2f((ushort_t)hv[j]) * Wfc[lane * 8 + j];
        #pragma unroll
        for (int off = 32; off; off >>= 1) s += __shfl_down(s, off, 64);
        if (lane == 0) out[rowbase + b] = s + bfc[0];
    }
}

// ---------------------------------------------------------------------------
extern "C" void kernel_launch(void* const* d_in, const int* in_sizes, int n_in,
                              void* d_out, int out_size, void* d_ws, size_t ws_size,
                              hipStream_t stream)
{
    const float* x   = (const float*)d_in[0];
    const float* Wx  = (const float*)d_in[1];
    const float* bx  = (const float*)d_in[2];
    const float* Wh  = (const float*)d_in[3];
    const float* bh  = (const float*)d_in[4];
    const float* Wfc = (const float*)d_in[5];
    const float* bfc = (const float*)d_in[6];
    float* out = (float*)d_out;

    // ws: xw bf16 [1024 t][64 b][512 n] = 64 MiB
    ushort_t* xw = (ushort_t*)d_ws;

    k1_xproj<<<dim3(512), 512, 0, stream>>>(x, Wx, bx, bh, xw);
    k2_scan <<<dim3(4),   512, 0, stream>>>(xw, Wh, Wfc, bfc, out);
}